// Round 23
// baseline (347.783 us; speedup 1.0000x reference)
//
#include <hip/hip_runtime.h>
#include <cmath>

#define B_ 4
#define T_ 8192
#define C_ 256
#define E_ 8
#define M_ (B_*T_)

typedef __bf16 bf16x8 __attribute__((ext_vector_type(8)));
typedef float  f32x4  __attribute__((ext_vector_type(4)));

typedef const __attribute__((address_space(1))) unsigned int* gas_t;
typedef __attribute__((address_space(3))) unsigned int* las_t;

static __device__ __forceinline__ unsigned short f2bf(float f) {
    union { float fv; unsigned u; } v; v.fv = f;
    unsigned r = v.u + 0x7FFFu + ((v.u >> 16) & 1u);
    return (unsigned short)(r >> 16);
}

// Abramowitz-Stegun 7.1.26: |err| <= 1.5e-7
static __device__ __forceinline__ float fast_erf(float x) {
    float ax = fabsf(x);
    float t = __builtin_amdgcn_rcpf(1.0f + 0.3275911f * ax);
    float p = ((((1.061405429f * t - 1.453152027f) * t) + 1.421413741f) * t - 0.284496736f) * t + 0.254829592f;
    float y = 1.0f - p * t * __expf(-ax * ax);
    return copysignf(y, x);
}

static __device__ __forceinline__ float gelu_f(float x) {
    return 0.5f * x * (1.0f + fast_erf(x * 0.7071067811865476f));
}

static __device__ __forceinline__ f32x4 mfma16(bf16x8 a, bf16x8 b, f32x4 c) {
    return __builtin_amdgcn_mfma_f32_16x16x32_bf16(a, b, c, 0, 0, 0);
}

// WAVE-PRIVATE strip stage: [64 cols][32 k] bf16 = 4KB, 4 x 16B loads by ONE wave.
// 16B-slot s holds (col = s>>2, ks = (s&3) ^ ((col>>1)&3)); read side
// slot = (col<<2) + (khi ^ ((col>>1)&3)) -> 2-way max bank aliasing (free,
// r9/r19-verified family). Only the staging wave reads the strip -> per-wave
// vmcnt ordering suffices, NO barrier. LDS dest linear; src pre-swizzled.
static __device__ __forceinline__ void stage_strip(const unsigned short* __restrict__ src,
                                                   unsigned short* base, int lane) {
#pragma unroll
    for (int j = 0; j < 4; j++) {
        int s = (j << 6) + lane;
        int col = s >> 2;
        int ks = (s & 3) ^ ((col >> 1) & 3);
        const unsigned short* gp = src + (col << 8) + (ks << 3);
        __builtin_amdgcn_global_load_lds((gas_t)(const void*)gp,
                                         (las_t)(void*)(base + (j << 9)), 16, 0, 0);
    }
}

// ---------------- prep kernels ----------------

__global__ void k_w1t(const float* __restrict__ W1, unsigned short* __restrict__ w1t) {
    __shared__ float tile[64][65];
    int e = blockIdx.x >> 4, kt = (blockIdx.x >> 2) & 3, ct = blockIdx.x & 3;
    int k0 = kt << 6, c0 = ct << 6;
    const float* src = W1 + ((size_t)e << 18) + ((size_t)k0 << 8) + c0;
    int r = threadIdx.x >> 6, col = threadIdx.x & 63;
#pragma unroll
    for (int i = 0; i < 16; i++)
        tile[r + i * 4][col] = src[(size_t)(r + i * 4) * 256 + col];
    __syncthreads();
    unsigned short* dst = w1t + (e << 16) + (c0 << 8) + k0;
#pragma unroll
    for (int i = 0; i < 16; i++)
        dst[(r + i * 4) * 256 + col] = f2bf(tile[col][r + i * 4]);
}

__global__ void k_w2t(const float* __restrict__ W2, unsigned short* __restrict__ w2t) {
    __shared__ float tile[64][65];
    int e = blockIdx.x >> 4, ct = (blockIdx.x >> 2) & 3, ft = blockIdx.x & 3;
    int c0 = ct << 6, f0 = ft << 6;
    const float* src = W2 + ((size_t)e << 16) + ((size_t)c0 << 8) + f0;
    int r = threadIdx.x >> 6, col = threadIdx.x & 63;
#pragma unroll
    for (int i = 0; i < 16; i++)
        tile[r + i * 4][col] = src[(size_t)(r + i * 4) * 256 + col];
    __syncthreads();
    unsigned short* dst = w2t + (e << 16) + (f0 << 8) + c0;
#pragma unroll
    for (int i = 0; i < 16; i++)
        dst[(r + i * 4) * 256 + col] = f2bf(tile[col][r + i * 4]);
}

// v2[e][c] = sum_f W2[e,c,f]*We[e,f];
// bc2[e] = -beta*( sum_f b2[e,f]*We[e,f] + be[e] + prior[e] );  bbeta[0] = beta
__global__ void k_v2(const float* __restrict__ W2, const float* __restrict__ We,
                     const float* __restrict__ b2, const float* __restrict__ be,
                     const float* __restrict__ log_beta, const float* __restrict__ prior,
                     float* __restrict__ v2, float* __restrict__ bc2, float* __restrict__ bbeta) {
    __shared__ float sm[4];
    int e = blockIdx.x >> 8, c = blockIdx.x & 255, f = threadIdx.x;
    float wef = We[(e << 8) + f];
    float v = W2[((((e << 8) + c) << 8)) + f] * wef;
#pragma unroll
    for (int m = 32; m >= 1; m >>= 1) v += __shfl_xor(v, m);
    if ((f & 63) == 0) sm[f >> 6] = v;
    __syncthreads();
    if (f == 0) v2[(e << 8) + c] = sm[0] + sm[1] + sm[2] + sm[3];
    if (c == 0) {
        __syncthreads();
        float u = b2[(e << 8) + f] * wef;
#pragma unroll
        for (int m = 32; m >= 1; m >>= 1) u += __shfl_xor(u, m);
        if ((f & 63) == 0) sm[f >> 6] = u;
        __syncthreads();
        if (f == 0) {
            float beta = __expf(log_beta[0]);
            float c2e = sm[0] + sm[1] + sm[2] + sm[3] + be[e];
            bc2[e] = -beta * (c2e + prior[e]);
            if (e == 0) bbeta[0] = beta;
        }
    }
}

__global__ void k_stats(const float* __restrict__ x, const int* __restrict__ mask,
                        const float* __restrict__ lnw, const float* __restrict__ lnb,
                        float* __restrict__ S1, float* __restrict__ S2, float* __restrict__ ncnt,
                        unsigned short* __restrict__ xb) {
    int b = blockIdx.x >> 6;
    int chunk = blockIdx.x & 63;
    int wid = threadIdx.x >> 6, lane = threadIdx.x & 63;
    int c0 = lane << 2;
    float4 w4 = *reinterpret_cast<const float4*>(lnw + c0);
    float4 b4 = *reinterpret_cast<const float4*>(lnb + c0);
    float a1[4] = {0,0,0,0}, a2[4] = {0,0,0,0};
    int cnt = 0;
    int tbase = chunk * 128;
    for (int r = wid; r < 128; r += 4) {
        int row = b * T_ + tbase + r;
        float4 xv = *reinterpret_cast<const float4*>(x + (size_t)row * C_ + c0);
        ushort4 o;
        o.x = f2bf(xv.x); o.y = f2bf(xv.y); o.z = f2bf(xv.z); o.w = f2bf(xv.w);
        *reinterpret_cast<ushort4*>(xb + (size_t)row * C_ + c0) = o;
        float s1 = xv.x + xv.y + xv.z + xv.w;
        float s2 = xv.x*xv.x + xv.y*xv.y + xv.z*xv.z + xv.w*xv.w;
#pragma unroll
        for (int m = 1; m < 64; m <<= 1) { s1 += __shfl_xor(s1, m); s2 += __shfl_xor(s2, m); }
        if (mask[row]) {
            float mu = s1 * (1.f / C_);
            float var = s2 * (1.f / C_) - mu * mu;
            float rs = rsqrtf(var + 1e-5f);
            float hv;
            hv = (xv.x - mu) * rs * w4.x + b4.x; a1[0] += hv; a2[0] += hv * hv;
            hv = (xv.y - mu) * rs * w4.y + b4.y; a1[1] += hv; a2[1] += hv * hv;
            hv = (xv.z - mu) * rs * w4.z + b4.z; a1[2] += hv; a2[2] += hv * hv;
            hv = (xv.w - mu) * rs * w4.w + b4.w; a1[3] += hv; a2[3] += hv * hv;
            cnt++;
        }
    }
    __shared__ float red[4][256];
    __shared__ int rc[4];
#pragma unroll
    for (int j = 0; j < 4; j++) red[wid][c0 + j] = a1[j];
    if (lane == 0) rc[wid] = cnt;
    __syncthreads();
    int ch = threadIdx.x;
    float s = red[0][ch] + red[1][ch] + red[2][ch] + red[3][ch];
    atomicAdd(&S1[(b << 8) + ch], s);
    if (threadIdx.x == 0) atomicAdd(&ncnt[b], (float)(rc[0] + rc[1] + rc[2] + rc[3]));
    __syncthreads();
#pragma unroll
    for (int j = 0; j < 4; j++) red[wid][c0 + j] = a2[j];
    __syncthreads();
    s = red[0][ch] + red[1][ch] + red[2][ch] + red[3][ch];
    atomicAdd(&S2[(b << 8) + ch], s);
}

__global__ void k_stats_fin(const float* __restrict__ S1, const float* __restrict__ S2,
                            const float* __restrict__ ncnt, float* __restrict__ stats) {
    int b = blockIdx.x, c = threadIdx.x;
    float n = fmaxf(ncnt[b], 1.f);
    float mean = S1[(b << 8) + c] / n;
    float var_b = fmaxf(S2[(b << 8) + c] / n - mean * mean, 0.f);
    float var_u = (n > 1.f) ? (var_b * (n / fmaxf(n - 1.f, 1e-9f))) : var_b;
    float std_u = fmaxf(sqrtf(var_u), 1e-9f);
    stats[b * 768 + 0 * 256 + c] = mean;
    stats[b * 768 + 1 * 256 + c] = std_u;
    stats[b * 768 + 2 * 256 + c] = var_u;
}

__global__ void k_bias(const float* __restrict__ W1, const float* __restrict__ b1,
                       const float* __restrict__ stats, float* __restrict__ bias) {
    int b = blockIdx.x >> 3, e = blockIdx.x & 7, c = threadIdx.x;
    __shared__ float sm[768];
    for (int i = threadIdx.x; i < 768; i += 256) sm[i] = stats[b * 768 + i];
    __syncthreads();
    const float* w = W1 + (size_t)e * 1024 * 256;
    float acc = b1[(e << 8) + c];
#pragma unroll 4
    for (int j = 0; j < 256; j++) {
        acc += sm[j]       * w[(256 + j) * 256 + c];
        acc += sm[256 + j] * w[(512 + j) * 256 + c];
        acc += sm[512 + j] * w[(768 + j) * 256 + c];
    }
    bias[((b << 3) + e) * 256 + c] = acc;
}

// ---------------- fused: GEMM1 + gelu + energy + online softmax + GEMM2 ----------------
// r22 structure (per-wave self-paced barrier-free strip pipelines, A/h1 shared
// 16KB LDS tile, 128-VGPR-fitting live set) with strips shrunk 8KB -> 4KB
// ([64 cols][32 k]): LDS = 4x2x4 + 16 = 48KB -> 3 blocks/CU = 12 waves/CU
// (r22's 80KB allowed only 2; occupancy was the residual limit at MfmaUtil 16%/
// VALUBusy 34%). 16 chunks/expert, vmcnt(4) uniform (stage = 4 loads, newest
// always left in flight). Boundary keeps the drain+barrier (cross-wave atile
// visibility needs it regardless).

__global__ __launch_bounds__(256, 3) void k_fused(
    const unsigned short* __restrict__ xb, const unsigned short* __restrict__ w1t,
    const unsigned short* __restrict__ w2t, const float* __restrict__ bias,
    const float* __restrict__ v2, const float* __restrict__ bc2,
    const float* __restrict__ bbeta, const int* __restrict__ mask,
    const float* __restrict__ b2, float* __restrict__ out) {
    __shared__ unsigned short sbuf[4][2][2048];  // per-wave double-buffered 4KB strips
    __shared__ unsigned short atile[8192];       // 16KB: A-tile (GEMM1) / h1 (GEMM2)
    float* scr = reinterpret_cast<float*>(&sbuf[0][1][0]);  // dead at tail (see r22 note)

    int row0 = blockIdx.x << 5;                  // 32 rows/block
    int b = row0 >> 13;
    int tid = threadIdx.x;
    int w = tid >> 6, lane = tid & 63;
    int nco = w << 6;                            // wave's col-strip base
    int rlo = lane & 15, khi = lane >> 4;
    unsigned short* buf0 = &sbuf[w][0][0];
    unsigned short* buf1 = &sbuf[w][1][0];

    float beta = bbeta[0];

    f32x4 acc2[2][4];
#pragma unroll
    for (int mt = 0; mt < 2; mt++)
#pragma unroll
        for (int nt = 0; nt < 4; nt++)
#pragma unroll
            for (int i = 0; i < 4; i++) acc2[mt][nt][i] = 0.f;
    float m_run[2][4], s_run[2][4];
#pragma unroll
    for (int mt = 0; mt < 2; mt++)
#pragma unroll
        for (int i = 0; i < 4; i++) { m_run[mt][i] = -3.0e38f; s_run[mt][i] = 0.f; }

    // prologue: stage own strip of chunk 0 (w1t e0 k-slab 0)
    asm volatile("" ::: "memory");
    stage_strip(w1t + (w << 14), buf0, lane);

    for (int e = 0; e < E_; e++) {
        if (e > 0) __builtin_amdgcn_s_barrier();   // all waves done GEMM2 h1 reads
        // ---- stage A-tile (x rows) into atile; 4 x 16B per wave; swizzled src ----
        // unit u holds (r = u>>5, col-unit = (u&24) | ((u&7) ^ (r&7)))
#pragma unroll
        for (int i = 0; i < 4; i++) {
            int u = (i << 8) + (w << 6) + lane;
            int r = u >> 5;
            int uc = (u & 24) | ((u & 7) ^ (r & 7));
            const unsigned short* gp = xb + (size_t)(row0 + r) * C_ + (uc << 3);
            __builtin_amdgcn_global_load_lds((gas_t)(const void*)gp,
                (las_t)(void*)(atile + (((i << 8) + (w << 6)) << 3)), 16, 0, 0);
        }
        // per-expert constants
        float bv[4], v2v[4], b2v[4];
#pragma unroll
        for (int nt = 0; nt < 4; nt++) {
            bv[nt]  = bias[(((b << 3) + e) << 8) + nco + (nt << 4) + rlo];
            v2v[nt] = v2[(e << 8) + nco + (nt << 4) + rlo];
            b2v[nt] = b2[(e << 8) + nco + (nt << 4) + rlo];
        }
        float bce = bc2[e];
        asm volatile("s_waitcnt vmcnt(0) lgkmcnt(0)" ::: "memory");
        __builtin_amdgcn_s_barrier();              // A-tile + strip(16e) resident

        f32x4 acc1[2][4];
#pragma unroll
        for (int mt = 0; mt < 2; mt++)
#pragma unroll
            for (int nt = 0; nt < 4; nt++)
#pragma unroll
                for (int i = 0; i < 4; i++) acc1[mt][nt][i] = 0.f;

        // ===== GEMM1: 8 barrier-free phases (chunk p = e*16+g, k-slab g) =====
#pragma unroll
        for (int g = 0; g < 8; g++) {
            int p = (e << 4) + g;
            int np = p + 1;
            {
                int q = np & 15;
                const unsigned short* nsrc = ((q & 8) ? w2t : w1t)
                    + ((np >> 4) << 16) + (w << 14) + ((q & 7) << 5);
                stage_strip(nsrc, (np & 1) ? buf1 : buf0, lane);
                asm volatile("s_waitcnt vmcnt(4)" ::: "memory");
            }
            const unsigned short* bs = (p & 1) ? buf1 : buf0;
            __builtin_amdgcn_s_setprio(1);
            bf16x8 a[2];
#pragma unroll
            for (int mt = 0; mt < 2; mt++) {
                int rowA = (mt << 4) + rlo;
                int byteoff = ((rowA << 9) + (g << 6) + (khi << 4)) ^ ((rowA & 7) << 4);
                a[mt] = *reinterpret_cast<const bf16x8*>(
                    reinterpret_cast<const char*>(atile) + byteoff);
            }
#pragma unroll
            for (int nt = 0; nt < 4; nt++) {
                int col = (nt << 4) + rlo;                 // strip-local col
                int slot = (col << 2) + (khi ^ ((col >> 1) & 3));
                bf16x8 bf = *reinterpret_cast<const bf16x8*>(bs + (slot << 3));
                acc1[0][nt] = mfma16(a[0], bf, acc1[0][nt]);
                acc1[1][nt] = mfma16(a[1], bf, acc1[1][nt]);
            }
            __builtin_amdgcn_s_setprio(0);
        }

        // ===== tail: bias + gelu + strip-energy + cross-strip reduce + softmax + h1 =====
        float rr[2][4], uu[2][4];
        {
            float epr[2][4];
#pragma unroll
            for (int mt = 0; mt < 2; mt++)
#pragma unroll
                for (int i = 0; i < 4; i++) {
                    float s = 0.f;
#pragma unroll
                    for (int nt = 0; nt < 4; nt++) {
                        float gl = gelu_f(acc1[mt][nt][i] + bv[nt]);
                        acc1[mt][nt][i] = gl;
                        s += gl * v2v[nt];
                    }
                    epr[mt][i] = s;
                }
#pragma unroll
            for (int m = 1; m < 16; m <<= 1)
#pragma unroll
                for (int mt = 0; mt < 2; mt++)
#pragma unroll
                    for (int i = 0; i < 4; i++) epr[mt][i] += __shfl_xor(epr[mt][i], m);
            __builtin_amdgcn_s_barrier();                  // B1: all waves done GEMM1
            // cross-strip exchange via scr (wave-0 buf1, dead after B1)
            if (rlo == 0) {
#pragma unroll
                for (int mt = 0; mt < 2; mt++)
#pragma unroll
                    for (int i = 0; i < 4; i++)
                        scr[(w << 5) + (mt << 4) + (khi << 2) + i] = epr[mt][i];
            }
            asm volatile("s_waitcnt lgkmcnt(0)" ::: "memory");
            __builtin_amdgcn_s_barrier();                  // B2: scr visible
#pragma unroll
            for (int mt = 0; mt < 2; mt++)
#pragma unroll
                for (int i = 0; i < 4; i++) {
                    int ridx = (mt << 4) + (khi << 2) + i;
                    float en = scr[ridx] + scr[32 + ridx] + scr[64 + ridx] + scr[96 + ridx];
                    float nb = -beta * en + bce;
                    float mn = fmaxf(m_run[mt][i], nb);
                    rr[mt][i] = __expf(m_run[mt][i] - mn);
                    uu[mt][i] = __expf(nb - mn);
                    s_run[mt][i] = s_run[mt][i] * rr[mt][i] + uu[mt][i];
                    m_run[mt][i] = mn;
                }
            // uu-scaled gelu(h1) -> atile region (A-tile dead post-B1), row-XOR
#pragma unroll
            for (int mt = 0; mt < 2; mt++)
#pragma unroll
                for (int i = 0; i < 4; i++) {
                    int rowl = (mt << 4) + (khi << 2) + i;
#pragma unroll
                    for (int nt = 0; nt < 4; nt++) {
                        int col = nco + (nt << 4) + rlo;
                        int byteoff = ((rowl << 9) + (col << 1)) ^ ((rowl & 7) << 4);
                        *reinterpret_cast<unsigned short*>(reinterpret_cast<char*>(atile) + byteoff)
                            = f2bf(acc1[mt][nt][i] * uu[mt][i]);
                    }
                }
            // GEMM2 acc init = uu*b2 (uu folded -> merge is 1 FMA)
#pragma unroll
            for (int mt = 0; mt < 2; mt++)
#pragma unroll
                for (int nt = 0; nt < 4; nt++)
#pragma unroll
                    for (int i = 0; i < 4; i++) acc1[mt][nt][i] = uu[mt][i] * b2v[nt];
        }
        asm volatile("s_waitcnt lgkmcnt(0)" ::: "memory");
        __builtin_amdgcn_s_barrier();                      // B3: h1 ready; scr reads done

        // ===== GEMM2: 8 barrier-free phases (chunk p = e*16+8+g, k-slab g of W2) =====
#pragma unroll
        for (int g = 0; g < 8; g++) {
            int p = (e << 4) + 8 + g;
            int np = p + 1;
            if (np < 128) {
                int q = np & 15;
                const unsigned short* nsrc = ((q & 8) ? w2t : w1t)
                    + ((np >> 4) << 16) + (w << 14) + ((q & 7) << 5);
                stage_strip(nsrc, (np & 1) ? buf1 : buf0, lane);
                asm volatile("s_waitcnt vmcnt(4)" ::: "memory");
            } else {
                asm volatile("s_waitcnt vmcnt(0)" ::: "memory");
            }
            const unsigned short* bs = (p & 1) ? buf1 : buf0;
            __builtin_amdgcn_s_setprio(1);
            bf16x8 a2[2];
#pragma unroll
            for (int mt = 0; mt < 2; mt++) {
                int rowA = (mt << 4) + rlo;
                int byteoff = ((rowA << 9) + (g << 6) + (khi << 4)) ^ ((rowA & 7) << 4);
                a2[mt] = *reinterpret_cast<const bf16x8*>(
                    reinterpret_cast<const char*>(atile) + byteoff);
            }
#pragma unroll
            for (int nt = 0; nt < 4; nt++) {
                int col = (nt << 4) + rlo;
                int slot = (col << 2) + (khi ^ ((col >> 1) & 3));
                bf16x8 bf = *reinterpret_cast<const bf16x8*>(bs + (slot << 3));
                acc1[0][nt] = mfma16(a2[0], bf, acc1[0][nt]);
                acc1[1][nt] = mfma16(a2[1], bf, acc1[1][nt]);
            }
            __builtin_amdgcn_s_setprio(0);
        }
        // merge: acc2 = acc2*rr + acc1 (uu already folded)
#pragma unroll
        for (int mt = 0; mt < 2; mt++)
#pragma unroll
            for (int nt = 0; nt < 4; nt++)
#pragma unroll
                for (int i = 0; i < 4; i++)
                    acc2[mt][nt][i] = acc2[mt][nt][i] * rr[mt][i] + acc1[mt][nt][i];
    }
    // ---- epilogue: divide by partition sum, mask ----
#pragma unroll
    for (int mt = 0; mt < 2; mt++)
#pragma unroll
        for (int i = 0; i < 4; i++) {
            int rowl = (mt << 4) + (khi << 2) + i;
            int mreg = mask[row0 + rowl];
            float si = mreg ? (1.0f / s_run[mt][i]) : 0.f;
            float* orow = out + (size_t)(row0 + rowl) * C_;
#pragma unroll
            for (int nt = 0; nt < 4; nt++)
                __builtin_nontemporal_store(acc2[mt][nt][i] * si,
                                            orow + nco + (nt << 4) + rlo);
        }
}

// ---------------- launch ----------------

extern "C" void kernel_launch(void* const* d_in, const int* in_sizes, int n_in,
                              void* d_out, int out_size, void* d_ws, size_t ws_size,
                              hipStream_t stream) {
    (void)in_sizes; (void)n_in; (void)out_size; (void)ws_size;
    const float* x        = (const float*)d_in[0];
    const int*   mask     = (const int*)d_in[1];
    const float* lnw      = (const float*)d_in[2];
    const float* lnb      = (const float*)d_in[3];
    const float* W1       = (const float*)d_in[4];
    const float* b1       = (const float*)d_in[5];
    const float* W2       = (const float*)d_in[6];
    const float* b2       = (const float*)d_in[7];
    const float* We       = (const float*)d_in[8];
    const float* be       = (const float*)d_in[9];
    const float* log_beta = (const float*)d_in[10];
    const float* prior    = (const float*)d_in[11];
    float* out = (float*)d_out;
    char* ws = (char*)d_ws;

    constexpr size_t OFF_XB    = 0;                       // 16 MB
    constexpr size_t OFF_W1T   = 16777216;                // 1 MB
    constexpr size_t OFF_W2T   = 17825792;                // 1 MB
    constexpr size_t OFF_V2    = 18874368;                // 8 KB
    constexpr size_t OFF_BC2   = 18882560;                // 32 B
    constexpr size_t OFF_S1    = 18882592;                // 4 KB
    constexpr size_t OFF_S2    = 18886688;                // 4 KB
    constexpr size_t OFF_N     = 18890784;                // 16 B
    constexpr size_t OFF_STATS = 18890800;                // 12 KB
    constexpr size_t OFF_BIAS  = 18903088;                // 32 KB
    constexpr size_t OFF_BB    = 18935856;                // 4 B

    unsigned short* xb  = (unsigned short*)(ws + OFF_XB);
    unsigned short* w1t = (unsigned short*)(ws + OFF_W1T);
    unsigned short* w2t = (unsigned short*)(ws + OFF_W2T);
    float* v2    = (float*)(ws + OFF_V2);
    float* bc2   = (float*)(ws + OFF_BC2);
    float* S1    = (float*)(ws + OFF_S1);
    float* S2    = (float*)(ws + OFF_S2);
    float* ncnt  = (float*)(ws + OFF_N);
    float* stats = (float*)(ws + OFF_STATS);
    float* bias  = (float*)(ws + OFF_BIAS);
    float* bbeta = (float*)(ws + OFF_BB);

    hipMemsetAsync(ws + OFF_S1, 0, 4096 + 4096 + 16, stream);

    k_w1t<<<128, 256, 0, stream>>>(W1, w1t);
    k_w2t<<<128, 256, 0, stream>>>(W2, w2t);
    k_v2<<<2048, 256, 0, stream>>>(W2, We, b2, be, log_beta, prior, v2, bc2, bbeta);
    k_stats<<<256, 256, 0, stream>>>(x, mask, lnw, lnb, S1, S2, ncnt, xb);
    k_stats_fin<<<4, 256, 0, stream>>>(S1, S2, ncnt, stats);
    k_bias<<<32, 256, 0, stream>>>(W1, b1, stats, bias);
    k_fused<<<1024, 256, 0, stream>>>(xb, w1t, w2t, bias, v2, bc2, bbeta, mask, b2, out);
}

// Round 24
// 208.954 us; speedup vs baseline: 1.6644x; 1.6644x over previous
//
#include <hip/hip_runtime.h>
#include <cmath>

#define B_ 4
#define T_ 8192
#define C_ 256
#define E_ 8
#define M_ (B_*T_)

typedef __bf16 bf16x8 __attribute__((ext_vector_type(8)));
typedef float  f32x4  __attribute__((ext_vector_type(4)));

typedef const __attribute__((address_space(1))) unsigned int* gas_t;
typedef __attribute__((address_space(3))) unsigned int* las_t;

static __device__ __forceinline__ unsigned short f2bf(float f) {
    union { float fv; unsigned u; } v; v.fv = f;
    unsigned r = v.u + 0x7FFFu + ((v.u >> 16) & 1u);
    return (unsigned short)(r >> 16);
}

// Abramowitz-Stegun 7.1.26: |err| <= 1.5e-7
static __device__ __forceinline__ float fast_erf(float x) {
    float ax = fabsf(x);
    float t = __builtin_amdgcn_rcpf(1.0f + 0.3275911f * ax);
    float p = ((((1.061405429f * t - 1.453152027f) * t) + 1.421413741f) * t - 0.284496736f) * t + 0.254829592f;
    float y = 1.0f - p * t * __expf(-ax * ax);
    return copysignf(y, x);
}

static __device__ __forceinline__ float gelu_f(float x) {
    return 0.5f * x * (1.0f + fast_erf(x * 0.7071067811865476f));
}

static __device__ __forceinline__ f32x4 mfma16(bf16x8 a, bf16x8 b, f32x4 c) {
    return __builtin_amdgcn_mfma_f32_16x16x32_bf16(a, b, c, 0, 0, 0);
}

// WAVE-PRIVATE strip stage: [64 cols][64 k] bf16 = 8KB, 8 x 16B loads by ONE wave.
// 16B-slot s holds (col = s>>3, ks = (s&7) ^ (col&7)); read side
// slot = (col<<3) + (ks ^ (col&7)) -> 2-way max bank aliasing (free). Only the
// staging wave reads the strip -> per-wave vmcnt ordering suffices, NO barrier.
static __device__ __forceinline__ void stage_strip(const unsigned short* __restrict__ src,
                                                   unsigned short* base, int lane) {
#pragma unroll
    for (int j = 0; j < 8; j++) {
        int s = (j << 6) + lane;
        int col = s >> 3;
        int ks = (s & 7) ^ (col & 7);
        const unsigned short* gp = src + (col << 8) + (ks << 3);
        __builtin_amdgcn_global_load_lds((gas_t)(const void*)gp,
                                         (las_t)(void*)(base + (j << 9)), 16, 0, 0);
    }
}

// ---------------- prep kernels ----------------

__global__ void k_w1t(const float* __restrict__ W1, unsigned short* __restrict__ w1t) {
    __shared__ float tile[64][65];
    int e = blockIdx.x >> 4, kt = (blockIdx.x >> 2) & 3, ct = blockIdx.x & 3;
    int k0 = kt << 6, c0 = ct << 6;
    const float* src = W1 + ((size_t)e << 18) + ((size_t)k0 << 8) + c0;
    int r = threadIdx.x >> 6, col = threadIdx.x & 63;
#pragma unroll
    for (int i = 0; i < 16; i++)
        tile[r + i * 4][col] = src[(size_t)(r + i * 4) * 256 + col];
    __syncthreads();
    unsigned short* dst = w1t + (e << 16) + (c0 << 8) + k0;
#pragma unroll
    for (int i = 0; i < 16; i++)
        dst[(r + i * 4) * 256 + col] = f2bf(tile[col][r + i * 4]);
}

__global__ void k_w2t(const float* __restrict__ W2, unsigned short* __restrict__ w2t) {
    __shared__ float tile[64][65];
    int e = blockIdx.x >> 4, ct = (blockIdx.x >> 2) & 3, ft = blockIdx.x & 3;
    int c0 = ct << 6, f0 = ft << 6;
    const float* src = W2 + ((size_t)e << 16) + ((size_t)c0 << 8) + f0;
    int r = threadIdx.x >> 6, col = threadIdx.x & 63;
#pragma unroll
    for (int i = 0; i < 16; i++)
        tile[r + i * 4][col] = src[(size_t)(r + i * 4) * 256 + col];
    __syncthreads();
    unsigned short* dst = w2t + (e << 16) + (f0 << 8) + c0;
#pragma unroll
    for (int i = 0; i < 16; i++)
        dst[(r + i * 4) * 256 + col] = f2bf(tile[col][r + i * 4]);
}

// v2[e][c] = sum_f W2[e,c,f]*We[e,f];
// bc2[e] = -beta*( sum_f b2[e,f]*We[e,f] + be[e] + prior[e] );  bbeta[0] = beta
__global__ void k_v2(const float* __restrict__ W2, const float* __restrict__ We,
                     const float* __restrict__ b2, const float* __restrict__ be,
                     const float* __restrict__ log_beta, const float* __restrict__ prior,
                     float* __restrict__ v2, float* __restrict__ bc2, float* __restrict__ bbeta) {
    __shared__ float sm[4];
    int e = blockIdx.x >> 8, c = blockIdx.x & 255, f = threadIdx.x;
    float wef = We[(e << 8) + f];
    float v = W2[((((e << 8) + c) << 8)) + f] * wef;
#pragma unroll
    for (int m = 32; m >= 1; m >>= 1) v += __shfl_xor(v, m);
    if ((f & 63) == 0) sm[f >> 6] = v;
    __syncthreads();
    if (f == 0) v2[(e << 8) + c] = sm[0] + sm[1] + sm[2] + sm[3];
    if (c == 0) {
        __syncthreads();
        float u = b2[(e << 8) + f] * wef;
#pragma unroll
        for (int m = 32; m >= 1; m >>= 1) u += __shfl_xor(u, m);
        if ((f & 63) == 0) sm[f >> 6] = u;
        __syncthreads();
        if (f == 0) {
            float beta = __expf(log_beta[0]);
            float c2e = sm[0] + sm[1] + sm[2] + sm[3] + be[e];
            bc2[e] = -beta * (c2e + prior[e]);
            if (e == 0) bbeta[0] = beta;
        }
    }
}

__global__ void k_stats(const float* __restrict__ x, const int* __restrict__ mask,
                        const float* __restrict__ lnw, const float* __restrict__ lnb,
                        float* __restrict__ S1, float* __restrict__ S2, float* __restrict__ ncnt,
                        unsigned short* __restrict__ xb) {
    int b = blockIdx.x >> 6;
    int chunk = blockIdx.x & 63;
    int wid = threadIdx.x >> 6, lane = threadIdx.x & 63;
    int c0 = lane << 2;
    float4 w4 = *reinterpret_cast<const float4*>(lnw + c0);
    float4 b4 = *reinterpret_cast<const float4*>(lnb + c0);
    float a1[4] = {0,0,0,0}, a2[4] = {0,0,0,0};
    int cnt = 0;
    int tbase = chunk * 128;
    for (int r = wid; r < 128; r += 4) {
        int row = b * T_ + tbase + r;
        float4 xv = *reinterpret_cast<const float4*>(x + (size_t)row * C_ + c0);
        ushort4 o;
        o.x = f2bf(xv.x); o.y = f2bf(xv.y); o.z = f2bf(xv.z); o.w = f2bf(xv.w);
        *reinterpret_cast<ushort4*>(xb + (size_t)row * C_ + c0) = o;
        float s1 = xv.x + xv.y + xv.z + xv.w;
        float s2 = xv.x*xv.x + xv.y*xv.y + xv.z*xv.z + xv.w*xv.w;
#pragma unroll
        for (int m = 1; m < 64; m <<= 1) { s1 += __shfl_xor(s1, m); s2 += __shfl_xor(s2, m); }
        if (mask[row]) {
            float mu = s1 * (1.f / C_);
            float var = s2 * (1.f / C_) - mu * mu;
            float rs = rsqrtf(var + 1e-5f);
            float hv;
            hv = (xv.x - mu) * rs * w4.x + b4.x; a1[0] += hv; a2[0] += hv * hv;
            hv = (xv.y - mu) * rs * w4.y + b4.y; a1[1] += hv; a2[1] += hv * hv;
            hv = (xv.z - mu) * rs * w4.z + b4.z; a1[2] += hv; a2[2] += hv * hv;
            hv = (xv.w - mu) * rs * w4.w + b4.w; a1[3] += hv; a2[3] += hv * hv;
            cnt++;
        }
    }
    __shared__ float red[4][256];
    __shared__ int rc[4];
#pragma unroll
    for (int j = 0; j < 4; j++) red[wid][c0 + j] = a1[j];
    if (lane == 0) rc[wid] = cnt;
    __syncthreads();
    int ch = threadIdx.x;
    float s = red[0][ch] + red[1][ch] + red[2][ch] + red[3][ch];
    atomicAdd(&S1[(b << 8) + ch], s);
    if (threadIdx.x == 0) atomicAdd(&ncnt[b], (float)(rc[0] + rc[1] + rc[2] + rc[3]));
    __syncthreads();
#pragma unroll
    for (int j = 0; j < 4; j++) red[wid][c0 + j] = a2[j];
    __syncthreads();
    s = red[0][ch] + red[1][ch] + red[2][ch] + red[3][ch];
    atomicAdd(&S2[(b << 8) + ch], s);
}

__global__ void k_stats_fin(const float* __restrict__ S1, const float* __restrict__ S2,
                            const float* __restrict__ ncnt, float* __restrict__ stats) {
    int b = blockIdx.x, c = threadIdx.x;
    float n = fmaxf(ncnt[b], 1.f);
    float mean = S1[(b << 8) + c] / n;
    float var_b = fmaxf(S2[(b << 8) + c] / n - mean * mean, 0.f);
    float var_u = (n > 1.f) ? (var_b * (n / fmaxf(n - 1.f, 1e-9f))) : var_b;
    float std_u = fmaxf(sqrtf(var_u), 1e-9f);
    stats[b * 768 + 0 * 256 + c] = mean;
    stats[b * 768 + 1 * 256 + c] = std_u;
    stats[b * 768 + 2 * 256 + c] = var_u;
}

__global__ void k_bias(const float* __restrict__ W1, const float* __restrict__ b1,
                       const float* __restrict__ stats, float* __restrict__ bias) {
    int b = blockIdx.x >> 3, e = blockIdx.x & 7, c = threadIdx.x;
    __shared__ float sm[768];
    for (int i = threadIdx.x; i < 768; i += 256) sm[i] = stats[b * 768 + i];
    __syncthreads();
    const float* w = W1 + (size_t)e * 1024 * 256;
    float acc = b1[(e << 8) + c];
#pragma unroll 4
    for (int j = 0; j < 256; j++) {
        acc += sm[j]       * w[(256 + j) * 256 + c];
        acc += sm[256 + j] * w[(512 + j) * 256 + c];
        acc += sm[512 + j] * w[(768 + j) * 256 + c];
    }
    bias[((b << 3) + e) * 256 + c] = acc;
}

// ---------------- fused: GEMM1 + gelu + energy + online softmax + GEMM2 ----------------
// BEST-MEASURED CONFIG (r22, 180us k_fused): per-wave self-paced barrier-free
// strip pipelines (8KB double-buffered [64c][64k] strips, vmcnt(8)); A moved to
// a 16KB LDS tile SHARED with h1 (never live together) so the live set (~115)
// fits the 128-VGPR cap at (256,2) -> 2 blocks/CU, spill-free (VGPR 120, WRITE
// = pure out). r23's (256,3)+4KB strips made the allocator drop to 84 VGPR and
// spill (WRITE 80MB, FETCH 203MB) -> reverted. This config is a narrow local
// optimum: {VGPR<=128, LDS=80KB, 2 blocks/CU, no spill, no per-phase barriers}.

__global__ __launch_bounds__(256, 2) void k_fused(
    const unsigned short* __restrict__ xb, const unsigned short* __restrict__ w1t,
    const unsigned short* __restrict__ w2t, const float* __restrict__ bias,
    const float* __restrict__ v2, const float* __restrict__ bc2,
    const float* __restrict__ bbeta, const int* __restrict__ mask,
    const float* __restrict__ b2, float* __restrict__ out) {
    __shared__ unsigned short sbuf[4][2][4096];  // per-wave double-buffered 8KB strips
    __shared__ unsigned short atile[8192];       // 16KB: A-tile (GEMM1) / h1 (GEMM2)
    float* scr = reinterpret_cast<float*>(&sbuf[0][1][0]);  // dead at tail (p=8e+3 consumed)

    int row0 = blockIdx.x << 5;                  // 32 rows/block
    int b = row0 >> 13;
    int tid = threadIdx.x;
    int w = tid >> 6, lane = tid & 63;
    int nco = w << 6;                            // wave's col-strip base
    int rlo = lane & 15, khi = lane >> 4;
    unsigned short* buf0 = &sbuf[w][0][0];
    unsigned short* buf1 = &sbuf[w][1][0];

    float beta = bbeta[0];

    f32x4 acc2[2][4];
#pragma unroll
    for (int mt = 0; mt < 2; mt++)
#pragma unroll
        for (int nt = 0; nt < 4; nt++)
#pragma unroll
            for (int i = 0; i < 4; i++) acc2[mt][nt][i] = 0.f;
    float m_run[2][4], s_run[2][4];
#pragma unroll
    for (int mt = 0; mt < 2; mt++)
#pragma unroll
        for (int i = 0; i < 4; i++) { m_run[mt][i] = -3.0e38f; s_run[mt][i] = 0.f; }

    // prologue: stage own strip of chunk 0 (w1t e0 k-slab 0)
    asm volatile("" ::: "memory");
    stage_strip(w1t + (w << 14), buf0, lane);

    for (int e = 0; e < E_; e++) {
        if (e > 0) __builtin_amdgcn_s_barrier();   // all waves done GEMM2 h1 reads
        // ---- stage A-tile (x rows) into atile; 4 x 16B per wave; swizzled src ----
        // unit u holds (r = u>>5, col-unit = (u&24) | ((u&7) ^ (r&7)))
#pragma unroll
        for (int i = 0; i < 4; i++) {
            int u = (i << 8) + (w << 6) + lane;
            int r = u >> 5;
            int uc = (u & 24) | ((u & 7) ^ (r & 7));
            const unsigned short* gp = xb + (size_t)(row0 + r) * C_ + (uc << 3);
            __builtin_amdgcn_global_load_lds((gas_t)(const void*)gp,
                (las_t)(void*)(atile + (((i << 8) + (w << 6)) << 3)), 16, 0, 0);
        }
        // per-expert constants
        float bv[4], v2v[4], b2v[4];
#pragma unroll
        for (int nt = 0; nt < 4; nt++) {
            bv[nt]  = bias[(((b << 3) + e) << 8) + nco + (nt << 4) + rlo];
            v2v[nt] = v2[(e << 8) + nco + (nt << 4) + rlo];
            b2v[nt] = b2[(e << 8) + nco + (nt << 4) + rlo];
        }
        float bce = bc2[e];
        asm volatile("s_waitcnt vmcnt(0) lgkmcnt(0)" ::: "memory");
        __builtin_amdgcn_s_barrier();              // A-tile + strip(8e) resident

        f32x4 acc1[2][4];
#pragma unroll
        for (int mt = 0; mt < 2; mt++)
#pragma unroll
            for (int nt = 0; nt < 4; nt++)
#pragma unroll
                for (int i = 0; i < 4; i++) acc1[mt][nt][i] = 0.f;

        // ===== GEMM1: 4 barrier-free phases (chunk p = e*8+g, k-slab g) =====
#pragma unroll
        for (int g = 0; g < 4; g++) {
            int p = (e << 3) + g;
            int np = p + 1;
            {
                int q = np & 7;
                const unsigned short* nsrc = ((q & 4) ? w2t : w1t)
                    + ((np >> 3) << 16) + (w << 14) + ((q & 3) << 6);
                stage_strip(nsrc, (np & 1) ? buf1 : buf0, lane);
                asm volatile("s_waitcnt vmcnt(8)" ::: "memory");
            }
            const unsigned short* bs = (p & 1) ? buf1 : buf0;
            __builtin_amdgcn_s_setprio(1);
#pragma unroll
            for (int kk2 = 0; kk2 < 2; kk2++) {
                int ks = (kk2 << 2) + khi;
                bf16x8 a[2];
#pragma unroll
                for (int mt = 0; mt < 2; mt++) {
                    int rowA = (mt << 4) + rlo;
                    int byteoff = ((rowA << 9) + (g << 7) + (kk2 << 6) + (khi << 4))
                                  ^ ((rowA & 7) << 4);
                    a[mt] = *reinterpret_cast<const bf16x8*>(
                        reinterpret_cast<const char*>(atile) + byteoff);
                }
#pragma unroll
                for (int nt = 0; nt < 4; nt++) {
                    int col = (nt << 4) + rlo;                 // strip-local col
                    int slot = (col << 3) + (ks ^ (col & 7));
                    bf16x8 bf = *reinterpret_cast<const bf16x8*>(bs + (slot << 3));
                    acc1[0][nt] = mfma16(a[0], bf, acc1[0][nt]);
                    acc1[1][nt] = mfma16(a[1], bf, acc1[1][nt]);
                }
            }
            __builtin_amdgcn_s_setprio(0);
        }

        // ===== tail: bias + gelu + strip-energy + cross-strip reduce + softmax + h1 =====
        float rr[2][4], uu[2][4];
        {
            float epr[2][4];
#pragma unroll
            for (int mt = 0; mt < 2; mt++)
#pragma unroll
                for (int i = 0; i < 4; i++) {
                    float s = 0.f;
#pragma unroll
                    for (int nt = 0; nt < 4; nt++) {
                        float gl = gelu_f(acc1[mt][nt][i] + bv[nt]);
                        acc1[mt][nt][i] = gl;
                        s += gl * v2v[nt];
                    }
                    epr[mt][i] = s;
                }
#pragma unroll
            for (int m = 1; m < 16; m <<= 1)
#pragma unroll
                for (int mt = 0; mt < 2; mt++)
#pragma unroll
                    for (int i = 0; i < 4; i++) epr[mt][i] += __shfl_xor(epr[mt][i], m);
            __builtin_amdgcn_s_barrier();                  // B1: all waves done GEMM1
            // cross-strip exchange via scr (wave-0 buf1, dead after B1)
            if (rlo == 0) {
#pragma unroll
                for (int mt = 0; mt < 2; mt++)
#pragma unroll
                    for (int i = 0; i < 4; i++)
                        scr[(w << 5) + (mt << 4) + (khi << 2) + i] = epr[mt][i];
            }
            asm volatile("s_waitcnt lgkmcnt(0)" ::: "memory");
            __builtin_amdgcn_s_barrier();                  // B2: scr visible
#pragma unroll
            for (int mt = 0; mt < 2; mt++)
#pragma unroll
                for (int i = 0; i < 4; i++) {
                    int ridx = (mt << 4) + (khi << 2) + i;
                    float en = scr[ridx] + scr[32 + ridx] + scr[64 + ridx] + scr[96 + ridx];
                    float nb = -beta * en + bce;
                    float mn = fmaxf(m_run[mt][i], nb);
                    rr[mt][i] = __expf(m_run[mt][i] - mn);
                    uu[mt][i] = __expf(nb - mn);
                    s_run[mt][i] = s_run[mt][i] * rr[mt][i] + uu[mt][i];
                    m_run[mt][i] = mn;
                }
            // uu-scaled gelu(h1) -> atile region (A-tile dead post-B1), row-XOR
#pragma unroll
            for (int mt = 0; mt < 2; mt++)
#pragma unroll
                for (int i = 0; i < 4; i++) {
                    int rowl = (mt << 4) + (khi << 2) + i;
#pragma unroll
                    for (int nt = 0; nt < 4; nt++) {
                        int col = nco + (nt << 4) + rlo;
                        int byteoff = ((rowl << 9) + (col << 1)) ^ ((rowl & 7) << 4);
                        *reinterpret_cast<unsigned short*>(reinterpret_cast<char*>(atile) + byteoff)
                            = f2bf(acc1[mt][nt][i] * uu[mt][i]);
                    }
                }
            // GEMM2 acc init = uu*b2 (uu folded -> merge is 1 FMA)
#pragma unroll
            for (int mt = 0; mt < 2; mt++)
#pragma unroll
                for (int nt = 0; nt < 4; nt++)
#pragma unroll
                    for (int i = 0; i < 4; i++) acc1[mt][nt][i] = uu[mt][i] * b2v[nt];
        }
        asm volatile("s_waitcnt lgkmcnt(0)" ::: "memory");
        __builtin_amdgcn_s_barrier();                      // B3: h1 ready; scr reads done

        // ===== GEMM2: 4 barrier-free phases (chunk p = e*8+4+g, k-slab g of W2) =====
#pragma unroll
        for (int g = 0; g < 4; g++) {
            int p = (e << 3) + 4 + g;
            int np = p + 1;
            if (np < 64) {
                int q = np & 7;
                const unsigned short* nsrc = ((q & 4) ? w2t : w1t)
                    + ((np >> 3) << 16) + (w << 14) + ((q & 3) << 6);
                stage_strip(nsrc, (np & 1) ? buf1 : buf0, lane);
                asm volatile("s_waitcnt vmcnt(8)" ::: "memory");
            } else {
                asm volatile("s_waitcnt vmcnt(0)" ::: "memory");
            }
            const unsigned short* bs = (p & 1) ? buf1 : buf0;
            __builtin_amdgcn_s_setprio(1);
#pragma unroll
            for (int kk2 = 0; kk2 < 2; kk2++) {
                int ks = (kk2 << 2) + khi;
                bf16x8 a2[2];
#pragma unroll
                for (int mt = 0; mt < 2; mt++) {
                    int rowA = (mt << 4) + rlo;
                    int byteoff = ((rowA << 9) + (g << 7) + (kk2 << 6) + (khi << 4))
                                  ^ ((rowA & 7) << 4);
                    a2[mt] = *reinterpret_cast<const bf16x8*>(
                        reinterpret_cast<const char*>(atile) + byteoff);
                }
#pragma unroll
                for (int nt = 0; nt < 4; nt++) {
                    int col = (nt << 4) + rlo;
                    int slot = (col << 3) + (ks ^ (col & 7));
                    bf16x8 bf = *reinterpret_cast<const bf16x8*>(bs + (slot << 3));
                    acc1[0][nt] = mfma16(a2[0], bf, acc1[0][nt]);
                    acc1[1][nt] = mfma16(a2[1], bf, acc1[1][nt]);
                }
            }
            __builtin_amdgcn_s_setprio(0);
        }
        // merge: acc2 = acc2*rr + acc1 (uu already folded)
#pragma unroll
        for (int mt = 0; mt < 2; mt++)
#pragma unroll
            for (int nt = 0; nt < 4; nt++)
#pragma unroll
                for (int i = 0; i < 4; i++)
                    acc2[mt][nt][i] = acc2[mt][nt][i] * rr[mt][i] + acc1[mt][nt][i];
    }
    // ---- epilogue: divide by partition sum, mask ----
#pragma unroll
    for (int mt = 0; mt < 2; mt++)
#pragma unroll
        for (int i = 0; i < 4; i++) {
            int rowl = (mt << 4) + (khi << 2) + i;
            int mreg = mask[row0 + rowl];
            float si = mreg ? (1.0f / s_run[mt][i]) : 0.f;
            float* orow = out + (size_t)(row0 + rowl) * C_;
#pragma unroll
            for (int nt = 0; nt < 4; nt++)
                __builtin_nontemporal_store(acc2[mt][nt][i] * si,
                                            orow + nco + (nt << 4) + rlo);
        }
}

// ---------------- launch ----------------

extern "C" void kernel_launch(void* const* d_in, const int* in_sizes, int n_in,
                              void* d_out, int out_size, void* d_ws, size_t ws_size,
                              hipStream_t stream) {
    (void)in_sizes; (void)n_in; (void)out_size; (void)ws_size;
    const float* x        = (const float*)d_in[0];
    const int*   mask     = (const int*)d_in[1];
    const float* lnw      = (const float*)d_in[2];
    const float* lnb      = (const float*)d_in[3];
    const float* W1       = (const float*)d_in[4];
    const float* b1       = (const float*)d_in[5];
    const float* W2       = (const float*)d_in[6];
    const float* b2       = (const float*)d_in[7];
    const float* We       = (const float*)d_in[8];
    const float* be       = (const float*)d_in[9];
    const float* log_beta = (const float*)d_in[10];
    const float* prior    = (const float*)d_in[11];
    float* out = (float*)d_out;
    char* ws = (char*)d_ws;

    constexpr size_t OFF_XB    = 0;                       // 16 MB
    constexpr size_t OFF_W1T   = 16777216;                // 1 MB
    constexpr size_t OFF_W2T   = 17825792;                // 1 MB
    constexpr size_t OFF_V2    = 18874368;                // 8 KB
    constexpr size_t OFF_BC2   = 18882560;                // 32 B
    constexpr size_t OFF_S1    = 18882592;                // 4 KB
    constexpr size_t OFF_S2    = 18886688;                // 4 KB
    constexpr size_t OFF_N     = 18890784;                // 16 B
    constexpr size_t OFF_STATS = 18890800;                // 12 KB
    constexpr size_t OFF_BIAS  = 18903088;                // 32 KB
    constexpr size_t OFF_BB    = 18935856;                // 4 B

    unsigned short* xb  = (unsigned short*)(ws + OFF_XB);
    unsigned short* w1t = (unsigned short*)(ws + OFF_W1T);
    unsigned short* w2t = (unsigned short*)(ws + OFF_W2T);
    float* v2    = (float*)(ws + OFF_V2);
    float* bc2   = (float*)(ws + OFF_BC2);
    float* S1    = (float*)(ws + OFF_S1);
    float* S2    = (float*)(ws + OFF_S2);
    float* ncnt  = (float*)(ws + OFF_N);
    float* stats = (float*)(ws + OFF_STATS);
    float* bias  = (float*)(ws + OFF_BIAS);
    float* bbeta = (float*)(ws + OFF_BB);

    hipMemsetAsync(ws + OFF_S1, 0, 4096 + 4096 + 16, stream);

    k_w1t<<<128, 256, 0, stream>>>(W1, w1t);
    k_w2t<<<128, 256, 0, stream>>>(W2, w2t);
    k_v2<<<2048, 256, 0, stream>>>(W2, We, b2, be, log_beta, prior, v2, bc2, bbeta);
    k_stats<<<256, 256, 0, stream>>>(x, mask, lnw, lnb, S1, S2, ncnt, xb);
    k_stats_fin<<<4, 256, 0, stream>>>(S1, S2, ncnt, stats);
    k_bias<<<32, 256, 0, stream>>>(W1, b1, stats, bias);
    k_fused<<<1024, 256, 0, stream>>>(xb, w1t, w2t, bias, v2, bc2, bbeta, mask, b2, out);
}

// Round 25
// 201.154 us; speedup vs baseline: 1.7289x; 1.0388x over previous
//
#include <hip/hip_runtime.h>
#include <cmath>

#define B_ 4
#define T_ 8192
#define C_ 256
#define E_ 8
#define M_ (B_*T_)

typedef __bf16 bf16x8 __attribute__((ext_vector_type(8)));
typedef float  f32x4  __attribute__((ext_vector_type(4)));

typedef const __attribute__((address_space(1))) unsigned int* gas_t;
typedef __attribute__((address_space(3))) unsigned int* las_t;

static __device__ __forceinline__ unsigned short f2bf(float f) {
    union { float fv; unsigned u; } v; v.fv = f;
    unsigned r = v.u + 0x7FFFu + ((v.u >> 16) & 1u);
    return (unsigned short)(r >> 16);
}

// Abramowitz-Stegun 7.1.26: |err| <= 1.5e-7
static __device__ __forceinline__ float fast_erf(float x) {
    float ax = fabsf(x);
    float t = __builtin_amdgcn_rcpf(1.0f + 0.3275911f * ax);
    float p = ((((1.061405429f * t - 1.453152027f) * t) + 1.421413741f) * t - 0.284496736f) * t + 0.254829592f;
    float y = 1.0f - p * t * __expf(-ax * ax);
    return copysignf(y, x);
}

static __device__ __forceinline__ float gelu_f(float x) {
    return 0.5f * x * (1.0f + fast_erf(x * 0.7071067811865476f));
}

static __device__ __forceinline__ f32x4 mfma16(bf16x8 a, bf16x8 b, f32x4 c) {
    return __builtin_amdgcn_mfma_f32_16x16x32_bf16(a, b, c, 0, 0, 0);
}

// WAVE-PRIVATE strip stage: [64 cols][64 k] bf16 = 8KB, 8 x 16B loads by ONE wave.
// 16B-slot s holds (col = s>>3, ks = (s&7) ^ (col&7)); read side
// slot = (col<<3) + (ks ^ (col&7)) -> 2-way max bank aliasing (free). Only the
// staging wave reads the strip -> per-wave vmcnt ordering suffices, NO barrier.
static __device__ __forceinline__ void stage_strip(const unsigned short* __restrict__ src,
                                                   unsigned short* base, int lane) {
#pragma unroll
    for (int j = 0; j < 8; j++) {
        int s = (j << 6) + lane;
        int col = s >> 3;
        int ks = (s & 7) ^ (col & 7);
        const unsigned short* gp = src + (col << 8) + (ks << 3);
        __builtin_amdgcn_global_load_lds((gas_t)(const void*)gp,
                                         (las_t)(void*)(base + (j << 9)), 16, 0, 0);
    }
}

// ---------------- prep kernels ----------------

// merged W1/W2 transpose (blocks 0..127: w1t, 128..255: w2t); block 0 also
// zeroes S1/S2/ncnt for k_stats (runs before it on the stream).
__global__ void k_wt(const float* __restrict__ W1, const float* __restrict__ W2,
                     unsigned short* __restrict__ w1t, unsigned short* __restrict__ w2t,
                     float* __restrict__ S1, float* __restrict__ S2, float* __restrict__ ncnt) {
    __shared__ float tile[64][65];
    int bid = blockIdx.x;
    if (bid == 0) {
        for (int i = threadIdx.x; i < 2052; i += 256) {
            if (i < 1024) S1[i] = 0.f;
            else if (i < 2048) S2[i - 1024] = 0.f;
            else ncnt[i - 2048] = 0.f;
        }
    }
    const float* srcW = (bid < 128) ? W1 : W2;
    unsigned short* dstW = (bid < 128) ? w1t : w2t;
    int lb = bid & 127;
    int e = lb >> 4, kt = (lb >> 2) & 3, ct = lb & 3;
    int k0 = kt << 6, c0 = ct << 6;
    size_t kstride = (bid < 128) ? ((size_t)1 << 18) : ((size_t)1 << 16);
    const float* src = srcW + (size_t)e * kstride + ((size_t)k0 << 8) + c0;
    int r = threadIdx.x >> 6, col = threadIdx.x & 63;
#pragma unroll
    for (int i = 0; i < 16; i++)
        tile[r + i * 4][col] = src[(size_t)(r + i * 4) * 256 + col];
    __syncthreads();
    unsigned short* dst = dstW + (e << 16) + (c0 << 8) + k0;
#pragma unroll
    for (int i = 0; i < 16; i++)
        dst[(r + i * 4) * 256 + col] = f2bf(tile[col][r + i * 4]);
}

// v2[e][c] = sum_f W2[e,c,f]*We[e,f];
// bc2[e] = -beta*( sum_f b2[e,f]*We[e,f] + be[e] + prior[e] );  bbeta[0] = beta
__global__ void k_v2(const float* __restrict__ W2, const float* __restrict__ We,
                     const float* __restrict__ b2, const float* __restrict__ be,
                     const float* __restrict__ log_beta, const float* __restrict__ prior,
                     float* __restrict__ v2, float* __restrict__ bc2, float* __restrict__ bbeta) {
    __shared__ float sm[4];
    int e = blockIdx.x >> 8, c = blockIdx.x & 255, f = threadIdx.x;
    float wef = We[(e << 8) + f];
    float v = W2[((((e << 8) + c) << 8)) + f] * wef;
#pragma unroll
    for (int m = 32; m >= 1; m >>= 1) v += __shfl_xor(v, m);
    if ((f & 63) == 0) sm[f >> 6] = v;
    __syncthreads();
    if (f == 0) v2[(e << 8) + c] = sm[0] + sm[1] + sm[2] + sm[3];
    if (c == 0) {
        __syncthreads();
        float u = b2[(e << 8) + f] * wef;
#pragma unroll
        for (int m = 32; m >= 1; m >>= 1) u += __shfl_xor(u, m);
        if ((f & 63) == 0) sm[f >> 6] = u;
        __syncthreads();
        if (f == 0) {
            float beta = __expf(log_beta[0]);
            float c2e = sm[0] + sm[1] + sm[2] + sm[3] + be[e];
            bc2[e] = -beta * (c2e + prior[e]);
            if (e == 0) bbeta[0] = beta;
        }
    }
}

__global__ void k_stats(const float* __restrict__ x, const int* __restrict__ mask,
                        const float* __restrict__ lnw, const float* __restrict__ lnb,
                        float* __restrict__ S1, float* __restrict__ S2, float* __restrict__ ncnt,
                        unsigned short* __restrict__ xb) {
    int b = blockIdx.x >> 6;
    int chunk = blockIdx.x & 63;
    int wid = threadIdx.x >> 6, lane = threadIdx.x & 63;
    int c0 = lane << 2;
    float4 w4 = *reinterpret_cast<const float4*>(lnw + c0);
    float4 b4 = *reinterpret_cast<const float4*>(lnb + c0);
    float a1[4] = {0,0,0,0}, a2[4] = {0,0,0,0};
    int cnt = 0;
    int tbase = chunk * 128;
    for (int r = wid; r < 128; r += 4) {
        int row = b * T_ + tbase + r;
        float4 xv = *reinterpret_cast<const float4*>(x + (size_t)row * C_ + c0);
        ushort4 o;
        o.x = f2bf(xv.x); o.y = f2bf(xv.y); o.z = f2bf(xv.z); o.w = f2bf(xv.w);
        *reinterpret_cast<ushort4*>(xb + (size_t)row * C_ + c0) = o;
        float s1 = xv.x + xv.y + xv.z + xv.w;
        float s2 = xv.x*xv.x + xv.y*xv.y + xv.z*xv.z + xv.w*xv.w;
#pragma unroll
        for (int m = 1; m < 64; m <<= 1) { s1 += __shfl_xor(s1, m); s2 += __shfl_xor(s2, m); }
        if (mask[row]) {
            float mu = s1 * (1.f / C_);
            float var = s2 * (1.f / C_) - mu * mu;
            float rs = rsqrtf(var + 1e-5f);
            float hv;
            hv = (xv.x - mu) * rs * w4.x + b4.x; a1[0] += hv; a2[0] += hv * hv;
            hv = (xv.y - mu) * rs * w4.y + b4.y; a1[1] += hv; a2[1] += hv * hv;
            hv = (xv.z - mu) * rs * w4.z + b4.z; a1[2] += hv; a2[2] += hv * hv;
            hv = (xv.w - mu) * rs * w4.w + b4.w; a1[3] += hv; a2[3] += hv * hv;
            cnt++;
        }
    }
    __shared__ float red[4][256];
    __shared__ int rc[4];
#pragma unroll
    for (int j = 0; j < 4; j++) red[wid][c0 + j] = a1[j];
    if (lane == 0) rc[wid] = cnt;
    __syncthreads();
    int ch = threadIdx.x;
    float s = red[0][ch] + red[1][ch] + red[2][ch] + red[3][ch];
    atomicAdd(&S1[(b << 8) + ch], s);
    if (threadIdx.x == 0) atomicAdd(&ncnt[b], (float)(rc[0] + rc[1] + rc[2] + rc[3]));
    __syncthreads();
#pragma unroll
    for (int j = 0; j < 4; j++) red[wid][c0 + j] = a2[j];
    __syncthreads();
    s = red[0][ch] + red[1][ch] + red[2][ch] + red[3][ch];
    atomicAdd(&S2[(b << 8) + ch], s);
}

// bias fold with stats finalization inlined (was k_stats_fin + k_bias)
__global__ void k_bias(const float* __restrict__ W1, const float* __restrict__ b1,
                       const float* __restrict__ S1, const float* __restrict__ S2,
                       const float* __restrict__ ncnt, float* __restrict__ bias) {
    int b = blockIdx.x >> 3, e = blockIdx.x & 7, c = threadIdx.x;
    __shared__ float sm[768];
    {
        float n = fmaxf(ncnt[b], 1.f);
        float mean = S1[(b << 8) + c] / n;
        float var_b = fmaxf(S2[(b << 8) + c] / n - mean * mean, 0.f);
        float var_u = (n > 1.f) ? (var_b * (n / fmaxf(n - 1.f, 1e-9f))) : var_b;
        float std_u = fmaxf(sqrtf(var_u), 1e-9f);
        sm[c] = mean;
        sm[256 + c] = std_u;
        sm[512 + c] = var_u;
    }
    __syncthreads();
    const float* w = W1 + (size_t)e * 1024 * 256;
    float acc = b1[(e << 8) + c];
#pragma unroll 4
    for (int j = 0; j < 256; j++) {
        acc += sm[j]       * w[(256 + j) * 256 + c];
        acc += sm[256 + j] * w[(512 + j) * 256 + c];
        acc += sm[512 + j] * w[(768 + j) * 256 + c];
    }
    bias[((b << 3) + e) * 256 + c] = acc;
}

// ---------------- fused: GEMM1 + gelu + energy + online softmax + GEMM2 ----------------
// BEST-MEASURED CONFIG (r22/r24, 180us): per-wave self-paced barrier-free strip
// pipelines (8KB double-buffered [64c][64k] strips, vmcnt(8)); A in a 16KB LDS
// tile SHARED with h1 (never live together) -> live set ~115 fits the 128-VGPR
// cap at (256,2) -> 2 blocks/CU, spill-free (VGPR 120, WRITE = pure out).
// Byte-identical to r24's k_fused.

__global__ __launch_bounds__(256, 2) void k_fused(
    const unsigned short* __restrict__ xb, const unsigned short* __restrict__ w1t,
    const unsigned short* __restrict__ w2t, const float* __restrict__ bias,
    const float* __restrict__ v2, const float* __restrict__ bc2,
    const float* __restrict__ bbeta, const int* __restrict__ mask,
    const float* __restrict__ b2, float* __restrict__ out) {
    __shared__ unsigned short sbuf[4][2][4096];  // per-wave double-buffered 8KB strips
    __shared__ unsigned short atile[8192];       // 16KB: A-tile (GEMM1) / h1 (GEMM2)
    float* scr = reinterpret_cast<float*>(&sbuf[0][1][0]);  // dead at tail (p=8e+3 consumed)

    int row0 = blockIdx.x << 5;                  // 32 rows/block
    int b = row0 >> 13;
    int tid = threadIdx.x;
    int w = tid >> 6, lane = tid & 63;
    int nco = w << 6;                            // wave's col-strip base
    int rlo = lane & 15, khi = lane >> 4;
    unsigned short* buf0 = &sbuf[w][0][0];
    unsigned short* buf1 = &sbuf[w][1][0];

    float beta = bbeta[0];

    f32x4 acc2[2][4];
#pragma unroll
    for (int mt = 0; mt < 2; mt++)
#pragma unroll
        for (int nt = 0; nt < 4; nt++)
#pragma unroll
            for (int i = 0; i < 4; i++) acc2[mt][nt][i] = 0.f;
    float m_run[2][4], s_run[2][4];
#pragma unroll
    for (int mt = 0; mt < 2; mt++)
#pragma unroll
        for (int i = 0; i < 4; i++) { m_run[mt][i] = -3.0e38f; s_run[mt][i] = 0.f; }

    // prologue: stage own strip of chunk 0 (w1t e0 k-slab 0)
    asm volatile("" ::: "memory");
    stage_strip(w1t + (w << 14), buf0, lane);

    for (int e = 0; e < E_; e++) {
        if (e > 0) __builtin_amdgcn_s_barrier();   // all waves done GEMM2 h1 reads
        // ---- stage A-tile (x rows) into atile; 4 x 16B per wave; swizzled src ----
        // unit u holds (r = u>>5, col-unit = (u&24) | ((u&7) ^ (r&7)))
#pragma unroll
        for (int i = 0; i < 4; i++) {
            int u = (i << 8) + (w << 6) + lane;
            int r = u >> 5;
            int uc = (u & 24) | ((u & 7) ^ (r & 7));
            const unsigned short* gp = xb + (size_t)(row0 + r) * C_ + (uc << 3);
            __builtin_amdgcn_global_load_lds((gas_t)(const void*)gp,
                (las_t)(void*)(atile + (((i << 8) + (w << 6)) << 3)), 16, 0, 0);
        }
        // per-expert constants
        float bv[4], v2v[4], b2v[4];
#pragma unroll
        for (int nt = 0; nt < 4; nt++) {
            bv[nt]  = bias[(((b << 3) + e) << 8) + nco + (nt << 4) + rlo];
            v2v[nt] = v2[(e << 8) + nco + (nt << 4) + rlo];
            b2v[nt] = b2[(e << 8) + nco + (nt << 4) + rlo];
        }
        float bce = bc2[e];
        asm volatile("s_waitcnt vmcnt(0) lgkmcnt(0)" ::: "memory");
        __builtin_amdgcn_s_barrier();              // A-tile + strip(8e) resident

        f32x4 acc1[2][4];
#pragma unroll
        for (int mt = 0; mt < 2; mt++)
#pragma unroll
            for (int nt = 0; nt < 4; nt++)
#pragma unroll
                for (int i = 0; i < 4; i++) acc1[mt][nt][i] = 0.f;

        // ===== GEMM1: 4 barrier-free phases (chunk p = e*8+g, k-slab g) =====
#pragma unroll
        for (int g = 0; g < 4; g++) {
            int p = (e << 3) + g;
            int np = p + 1;
            {
                int q = np & 7;
                const unsigned short* nsrc = ((q & 4) ? w2t : w1t)
                    + ((np >> 3) << 16) + (w << 14) + ((q & 3) << 6);
                stage_strip(nsrc, (np & 1) ? buf1 : buf0, lane);
                asm volatile("s_waitcnt vmcnt(8)" ::: "memory");
            }
            const unsigned short* bs = (p & 1) ? buf1 : buf0;
            __builtin_amdgcn_s_setprio(1);
#pragma unroll
            for (int kk2 = 0; kk2 < 2; kk2++) {
                int ks = (kk2 << 2) + khi;
                bf16x8 a[2];
#pragma unroll
                for (int mt = 0; mt < 2; mt++) {
                    int rowA = (mt << 4) + rlo;
                    int byteoff = ((rowA << 9) + (g << 7) + (kk2 << 6) + (khi << 4))
                                  ^ ((rowA & 7) << 4);
                    a[mt] = *reinterpret_cast<const bf16x8*>(
                        reinterpret_cast<const char*>(atile) + byteoff);
                }
#pragma unroll
                for (int nt = 0; nt < 4; nt++) {
                    int col = (nt << 4) + rlo;                 // strip-local col
                    int slot = (col << 3) + (ks ^ (col & 7));
                    bf16x8 bf = *reinterpret_cast<const bf16x8*>(bs + (slot << 3));
                    acc1[0][nt] = mfma16(a[0], bf, acc1[0][nt]);
                    acc1[1][nt] = mfma16(a[1], bf, acc1[1][nt]);
                }
            }
            __builtin_amdgcn_s_setprio(0);
        }

        // ===== tail: bias + gelu + strip-energy + cross-strip reduce + softmax + h1 =====
        float rr[2][4], uu[2][4];
        {
            float epr[2][4];
#pragma unroll
            for (int mt = 0; mt < 2; mt++)
#pragma unroll
                for (int i = 0; i < 4; i++) {
                    float s = 0.f;
#pragma unroll
                    for (int nt = 0; nt < 4; nt++) {
                        float gl = gelu_f(acc1[mt][nt][i] + bv[nt]);
                        acc1[mt][nt][i] = gl;
                        s += gl * v2v[nt];
                    }
                    epr[mt][i] = s;
                }
#pragma unroll
            for (int m = 1; m < 16; m <<= 1)
#pragma unroll
                for (int mt = 0; mt < 2; mt++)
#pragma unroll
                    for (int i = 0; i < 4; i++) epr[mt][i] += __shfl_xor(epr[mt][i], m);
            __builtin_amdgcn_s_barrier();                  // B1: all waves done GEMM1
            // cross-strip exchange via scr (wave-0 buf1, dead after B1)
            if (rlo == 0) {
#pragma unroll
                for (int mt = 0; mt < 2; mt++)
#pragma unroll
                    for (int i = 0; i < 4; i++)
                        scr[(w << 5) + (mt << 4) + (khi << 2) + i] = epr[mt][i];
            }
            asm volatile("s_waitcnt lgkmcnt(0)" ::: "memory");
            __builtin_amdgcn_s_barrier();                  // B2: scr visible
#pragma unroll
            for (int mt = 0; mt < 2; mt++)
#pragma unroll
                for (int i = 0; i < 4; i++) {
                    int ridx = (mt << 4) + (khi << 2) + i;
                    float en = scr[ridx] + scr[32 + ridx] + scr[64 + ridx] + scr[96 + ridx];
                    float nb = -beta * en + bce;
                    float mn = fmaxf(m_run[mt][i], nb);
                    rr[mt][i] = __expf(m_run[mt][i] - mn);
                    uu[mt][i] = __expf(nb - mn);
                    s_run[mt][i] = s_run[mt][i] * rr[mt][i] + uu[mt][i];
                    m_run[mt][i] = mn;
                }
            // uu-scaled gelu(h1) -> atile region (A-tile dead post-B1), row-XOR
#pragma unroll
            for (int mt = 0; mt < 2; mt++)
#pragma unroll
                for (int i = 0; i < 4; i++) {
                    int rowl = (mt << 4) + (khi << 2) + i;
#pragma unroll
                    for (int nt = 0; nt < 4; nt++) {
                        int col = nco + (nt << 4) + rlo;
                        int byteoff = ((rowl << 9) + (col << 1)) ^ ((rowl & 7) << 4);
                        *reinterpret_cast<unsigned short*>(reinterpret_cast<char*>(atile) + byteoff)
                            = f2bf(acc1[mt][nt][i] * uu[mt][i]);
                    }
                }
            // GEMM2 acc init = uu*b2 (uu folded -> merge is 1 FMA)
#pragma unroll
            for (int mt = 0; mt < 2; mt++)
#pragma unroll
                for (int nt = 0; nt < 4; nt++)
#pragma unroll
                    for (int i = 0; i < 4; i++) acc1[mt][nt][i] = uu[mt][i] * b2v[nt];
        }
        asm volatile("s_waitcnt lgkmcnt(0)" ::: "memory");
        __builtin_amdgcn_s_barrier();                      // B3: h1 ready; scr reads done

        // ===== GEMM2: 4 barrier-free phases (chunk p = e*8+4+g, k-slab g of W2) =====
#pragma unroll
        for (int g = 0; g < 4; g++) {
            int p = (e << 3) + 4 + g;
            int np = p + 1;
            if (np < 64) {
                int q = np & 7;
                const unsigned short* nsrc = ((q & 4) ? w2t : w1t)
                    + ((np >> 3) << 16) + (w << 14) + ((q & 3) << 6);
                stage_strip(nsrc, (np & 1) ? buf1 : buf0, lane);
                asm volatile("s_waitcnt vmcnt(8)" ::: "memory");
            } else {
                asm volatile("s_waitcnt vmcnt(0)" ::: "memory");
            }
            const unsigned short* bs = (p & 1) ? buf1 : buf0;
            __builtin_amdgcn_s_setprio(1);
#pragma unroll
            for (int kk2 = 0; kk2 < 2; kk2++) {
                int ks = (kk2 << 2) + khi;
                bf16x8 a2[2];
#pragma unroll
                for (int mt = 0; mt < 2; mt++) {
                    int rowA = (mt << 4) + rlo;
                    int byteoff = ((rowA << 9) + (g << 7) + (kk2 << 6) + (khi << 4))
                                  ^ ((rowA & 7) << 4);
                    a2[mt] = *reinterpret_cast<const bf16x8*>(
                        reinterpret_cast<const char*>(atile) + byteoff);
                }
#pragma unroll
                for (int nt = 0; nt < 4; nt++) {
                    int col = (nt << 4) + rlo;
                    int slot = (col << 3) + (ks ^ (col & 7));
                    bf16x8 bf = *reinterpret_cast<const bf16x8*>(bs + (slot << 3));
                    acc1[0][nt] = mfma16(a2[0], bf, acc1[0][nt]);
                    acc1[1][nt] = mfma16(a2[1], bf, acc1[1][nt]);
                }
            }
            __builtin_amdgcn_s_setprio(0);
        }
        // merge: acc2 = acc2*rr + acc1 (uu already folded)
#pragma unroll
        for (int mt = 0; mt < 2; mt++)
#pragma unroll
            for (int nt = 0; nt < 4; nt++)
#pragma unroll
                for (int i = 0; i < 4; i++)
                    acc2[mt][nt][i] = acc2[mt][nt][i] * rr[mt][i] + acc1[mt][nt][i];
    }
    // ---- epilogue: divide by partition sum, mask ----
#pragma unroll
    for (int mt = 0; mt < 2; mt++)
#pragma unroll
        for (int i = 0; i < 4; i++) {
            int rowl = (mt << 4) + (khi << 2) + i;
            int mreg = mask[row0 + rowl];
            float si = mreg ? (1.0f / s_run[mt][i]) : 0.f;
            float* orow = out + (size_t)(row0 + rowl) * C_;
#pragma unroll
            for (int nt = 0; nt < 4; nt++)
                __builtin_nontemporal_store(acc2[mt][nt][i] * si,
                                            orow + nco + (nt << 4) + rlo);
        }
}

// ---------------- launch ----------------

extern "C" void kernel_launch(void* const* d_in, const int* in_sizes, int n_in,
                              void* d_out, int out_size, void* d_ws, size_t ws_size,
                              hipStream_t stream) {
    (void)in_sizes; (void)n_in; (void)out_size; (void)ws_size;
    const float* x        = (const float*)d_in[0];
    const int*   mask     = (const int*)d_in[1];
    const float* lnw      = (const float*)d_in[2];
    const float* lnb      = (const float*)d_in[3];
    const float* W1       = (const float*)d_in[4];
    const float* b1       = (const float*)d_in[5];
    const float* W2       = (const float*)d_in[6];
    const float* b2       = (const float*)d_in[7];
    const float* We       = (const float*)d_in[8];
    const float* be       = (const float*)d_in[9];
    const float* log_beta = (const float*)d_in[10];
    const float* prior    = (const float*)d_in[11];
    float* out = (float*)d_out;
    char* ws = (char*)d_ws;

    constexpr size_t OFF_XB    = 0;                       // 16 MB
    constexpr size_t OFF_W1T   = 16777216;                // 1 MB
    constexpr size_t OFF_W2T   = 17825792;                // 1 MB
    constexpr size_t OFF_V2    = 18874368;                // 8 KB
    constexpr size_t OFF_BC2   = 18882560;                // 32 B
    constexpr size_t OFF_S1    = 18882592;                // 4 KB
    constexpr size_t OFF_S2    = 18886688;                // 4 KB
    constexpr size_t OFF_N     = 18890784;                // 16 B
    constexpr size_t OFF_BIAS  = 18903088;                // 32 KB
    constexpr size_t OFF_BB    = 18935856;                // 4 B

    unsigned short* xb  = (unsigned short*)(ws + OFF_XB);
    unsigned short* w1t = (unsigned short*)(ws + OFF_W1T);
    unsigned short* w2t = (unsigned short*)(ws + OFF_W2T);
    float* v2    = (float*)(ws + OFF_V2);
    float* bc2   = (float*)(ws + OFF_BC2);
    float* S1    = (float*)(ws + OFF_S1);
    float* S2    = (float*)(ws + OFF_S2);
    float* ncnt  = (float*)(ws + OFF_N);
    float* bias  = (float*)(ws + OFF_BIAS);
    float* bbeta = (float*)(ws + OFF_BB);

    k_wt<<<256, 256, 0, stream>>>(W1, W2, w1t, w2t, S1, S2, ncnt);
    k_v2<<<2048, 256, 0, stream>>>(W2, We, b2, be, log_beta, prior, v2, bc2, bbeta);
    k_stats<<<256, 256, 0, stream>>>(x, mask, lnw, lnb, S1, S2, ncnt, xb);
    k_bias<<<32, 256, 0, stream>>>(W1, b1, S1, S2, ncnt, bias);
    k_fused<<<1024, 256, 0, stream>>>(xb, w1t, w2t, bias, v2, bc2, bbeta, mask, b2, out);
}